// Round 2
// baseline (897.077 us; speedup 1.0000x reference)
//
#include <hip/hip_runtime.h>
#include <hip/hip_bf16.h>

#define NU 100000
#define NI 50000
#define NE 819200
#define FIN 128
#define HH 32

// ---- degree counts (f32 atomics; counts << 2^24 so exact) ----
__global__ void count_k(const int* __restrict__ eu, const int* __restrict__ ei,
                        float* __restrict__ cntU, float* __restrict__ cntI) {
    int e = blockIdx.x * 256 + threadIdx.x;
    if (e < NE) {
        atomicAdd(cntU + eu[e], 1.0f);
        atomicAdd(cntI + ei[e], 1.0f);
    }
}

// ---- Y[N,32] = X[N,128] @ W[32,128]^T  (f32 in/out) ----
// block = 256 threads = 8 nodes x 32 outputs; N divisible by 8
__global__ void proj128_k(const float* __restrict__ X,
                          const float* __restrict__ W,
                          float* __restrict__ Y) {
    __shared__ float sW[FIN * HH];   // sW[k*32+o] (transposed: broadcast/conflict-free)
    __shared__ float sX[8][FIN];
    int tid = threadIdx.x;
    const float4* W4 = (const float4*)W;
    for (int idx = tid; idx < (HH * FIN) / 4; idx += 256) {
        float4 w = W4[idx];
        int e0 = idx * 4;
        int o = e0 >> 7, k = e0 & 127;
        sW[k * HH + o] = w.x;
        sW[(k + 1) * HH + o] = w.y;
        sW[(k + 2) * HH + o] = w.z;
        sW[(k + 3) * HH + o] = w.w;
    }
    int n0 = blockIdx.x * 8;
    {
        const float4* X4 = (const float4*)(X + (long long)n0 * FIN);
        float4 v = X4[tid];                 // 256 float4 = 8 rows x 32
        int n = tid >> 5, k = (tid & 31) * 4;
        sX[n][k] = v.x; sX[n][k + 1] = v.y; sX[n][k + 2] = v.z; sX[n][k + 3] = v.w;
    }
    __syncthreads();
    int n = tid >> 5, c = tid & 31;
    float acc = 0.0f;
#pragma unroll
    for (int k = 0; k < FIN; ++k) acc += sX[n][k] * sW[k * HH + c];
    Y[(long long)(n0 + n) * HH + c] = acc;
}

// ---- edge scatter, both directions: aggI += Su[eu], aggU += Si[ei] ----
__global__ void scatter2_k(const int* __restrict__ eu, const int* __restrict__ ei,
                           const float* __restrict__ Su, const float* __restrict__ Si,
                           float* __restrict__ aggI, float* __restrict__ aggU) {
    long long g = (long long)blockIdx.x * 256 + threadIdx.x;
    int e = (int)(g >> 5), c = (int)(g & 31);
    int u = eu[e], i = ei[e];
    atomicAdd(aggI + (long long)i * HH + c, Su[(long long)u * HH + c]);
    atomicAdd(aggU + (long long)u * HH + c, Si[(long long)i * HH + c]);
}

// ---- out = relu(l2norm(agg/cnt + b + Xd[N,128] @ Wr[32,128]^T)), f32 out ----
__global__ void finish128_k(const float* __restrict__ agg, const float* __restrict__ cnt,
                            const float* __restrict__ b,
                            const float* __restrict__ Xd,
                            const float* __restrict__ Wr,
                            float* __restrict__ out) {
    __shared__ float sW[FIN * HH];
    __shared__ float sX[8][FIN];
    int tid = threadIdx.x;
    const float4* W4 = (const float4*)Wr;
    for (int idx = tid; idx < (HH * FIN) / 4; idx += 256) {
        float4 w = W4[idx];
        int e0 = idx * 4;
        int o = e0 >> 7, k = e0 & 127;
        sW[k * HH + o] = w.x;
        sW[(k + 1) * HH + o] = w.y;
        sW[(k + 2) * HH + o] = w.z;
        sW[(k + 3) * HH + o] = w.w;
    }
    int n0 = blockIdx.x * 8;
    {
        const float4* X4 = (const float4*)(Xd + (long long)n0 * FIN);
        float4 v = X4[tid];
        int n = tid >> 5, k = (tid & 31) * 4;
        sX[n][k] = v.x; sX[n][k + 1] = v.y; sX[n][k + 2] = v.z; sX[n][k + 3] = v.w;
    }
    __syncthreads();
    int n = tid >> 5, c = tid & 31;
    int node = n0 + n;
    float acc = 0.0f;
#pragma unroll
    for (int k = 0; k < FIN; ++k) acc += sX[n][k] * sW[k * HH + c];
    float cn = cnt[node];
    cn = cn > 1.0f ? cn : 1.0f;
    float v = agg[(long long)node * HH + c] / cn + b[c] + acc;
    float ss = v * v;
    ss += __shfl_xor(ss, 1);
    ss += __shfl_xor(ss, 2);
    ss += __shfl_xor(ss, 4);
    ss += __shfl_xor(ss, 8);
    ss += __shfl_xor(ss, 16);
    float nrm = sqrtf(ss);
    nrm = nrm > 1e-12f ? nrm : 1e-12f;
    v = v / nrm;
    v = v > 0.0f ? v : 0.0f;
    out[(long long)node * HH + c] = v;
}

// ---- Y[N,32] = X[N,32] @ W[32,32]^T ----
__global__ void proj32_k(const float* __restrict__ X,
                         const float* __restrict__ W,
                         float* __restrict__ Y) {
    __shared__ float sW[HH * HH];   // sW[k*32+o]
    __shared__ float sX[8][HH];
    int tid = threadIdx.x;
    if (tid < HH * HH / 4) {
        float4 w = ((const float4*)W)[tid];
        int e0 = tid * 4;
        int o = e0 >> 5, k = e0 & 31;
        sW[k * HH + o] = w.x;
        sW[(k + 1) * HH + o] = w.y;
        sW[(k + 2) * HH + o] = w.z;
        sW[(k + 3) * HH + o] = w.w;
    }
    int n0 = blockIdx.x * 8;
    {
        int n = tid >> 5, k = tid & 31;
        sX[n][k] = X[(long long)(n0 + n) * HH + k];
    }
    __syncthreads();
    int n = tid >> 5, c = tid & 31;
    float acc = 0.0f;
#pragma unroll
    for (int k = 0; k < HH; ++k) acc += sX[n][k] * sW[k * HH + c];
    Y[(long long)(n0 + n) * HH + c] = acc;
}

// ---- out = relu(l2norm(agg/cnt + b + Xd[N,32] @ Wr[32,32]^T)), in-place over agg ok ----
__global__ void finish32_k(const float* __restrict__ agg, const float* __restrict__ cnt,
                           const float* __restrict__ b,
                           const float* __restrict__ Xd,
                           const float* __restrict__ Wr,
                           float* __restrict__ out) {
    __shared__ float sW[HH * HH];
    __shared__ float sX[8][HH];
    int tid = threadIdx.x;
    if (tid < HH * HH / 4) {
        float4 w = ((const float4*)Wr)[tid];
        int e0 = tid * 4;
        int o = e0 >> 5, k = e0 & 31;
        sW[k * HH + o] = w.x;
        sW[(k + 1) * HH + o] = w.y;
        sW[(k + 2) * HH + o] = w.z;
        sW[(k + 3) * HH + o] = w.w;
    }
    int n0 = blockIdx.x * 8;
    {
        int n = tid >> 5, k = tid & 31;
        sX[n][k] = Xd[(long long)(n0 + n) * HH + k];
    }
    __syncthreads();
    int n = tid >> 5, c = tid & 31;
    int node = n0 + n;
    float acc = 0.0f;
#pragma unroll
    for (int k = 0; k < HH; ++k) acc += sX[n][k] * sW[k * HH + c];
    float cn = cnt[node];
    cn = cn > 1.0f ? cn : 1.0f;
    float v = agg[(long long)node * HH + c] / cn + b[c] + acc;
    float ss = v * v;
    ss += __shfl_xor(ss, 1);
    ss += __shfl_xor(ss, 2);
    ss += __shfl_xor(ss, 4);
    ss += __shfl_xor(ss, 8);
    ss += __shfl_xor(ss, 16);
    float nrm = sqrtf(ss);
    nrm = nrm > 1e-12f ? nrm : 1e-12f;
    v = v / nrm;
    v = v > 0.0f ? v : 0.0f;
    out[(long long)node * HH + c] = v;
}

// ---- emb = l2norm(X[N,32] @ W[32,32]^T + b), f32 out (no relu) ----
__global__ void final_k(const float* __restrict__ X,
                        const float* __restrict__ W,
                        const float* __restrict__ b,
                        float* __restrict__ out) {
    __shared__ float sW[HH * HH];
    __shared__ float sX[8][HH];
    int tid = threadIdx.x;
    if (tid < HH * HH / 4) {
        float4 w = ((const float4*)W)[tid];
        int e0 = tid * 4;
        int o = e0 >> 5, k = e0 & 31;
        sW[k * HH + o] = w.x;
        sW[(k + 1) * HH + o] = w.y;
        sW[(k + 2) * HH + o] = w.z;
        sW[(k + 3) * HH + o] = w.w;
    }
    int n0 = blockIdx.x * 8;
    {
        int n = tid >> 5, k = tid & 31;
        sX[n][k] = X[(long long)(n0 + n) * HH + k];
    }
    __syncthreads();
    int n = tid >> 5, c = tid & 31;
    float acc = b[c];
#pragma unroll
    for (int k = 0; k < HH; ++k) acc += sX[n][k] * sW[k * HH + c];
    float ss = acc * acc;
    ss += __shfl_xor(ss, 1);
    ss += __shfl_xor(ss, 2);
    ss += __shfl_xor(ss, 4);
    ss += __shfl_xor(ss, 8);
    ss += __shfl_xor(ss, 16);
    float nrm = sqrtf(ss);
    nrm = nrm > 1e-12f ? nrm : 1e-12f;
    out[(long long)(n0 + n) * HH + c] = acc / nrm;
}

extern "C" void kernel_launch(void* const* d_in, const int* in_sizes, int n_in,
                              void* d_out, int out_size, void* d_ws, size_t ws_size,
                              hipStream_t stream) {
    const float* x_user = (const float*)d_in[0];
    const float* x_item = (const float*)d_in[1];
    const int* eu = (const int*)d_in[2];
    const int* ei = (const int*)d_in[3];
    const float* wl0_ui = (const float*)d_in[4];
    const float* b0_ui  = (const float*)d_in[5];
    const float* wr0_ui = (const float*)d_in[6];
    const float* wl0_iu = (const float*)d_in[7];
    const float* b0_iu  = (const float*)d_in[8];
    const float* wr0_iu = (const float*)d_in[9];
    const float* wl1_ui = (const float*)d_in[10];
    const float* b1_ui  = (const float*)d_in[11];
    const float* wr1_ui = (const float*)d_in[12];
    const float* wl1_iu = (const float*)d_in[13];
    const float* b1_iu  = (const float*)d_in[14];
    const float* wr1_iu = (const float*)d_in[15];
    const float* wp_user = (const float*)d_in[16];
    const float* bp_user = (const float*)d_in[17];
    const float* wp_item = (const float*)d_in[18];
    const float* bp_item = (const float*)d_in[19];
    float* out = (float*)d_out;

    // workspace layout (256B-aligned), zero-region [cntU .. aggI] contiguous
    char* base = (char*)d_ws;
    size_t off = 0;
    auto take = [&](size_t bytes) -> size_t {
        size_t o = off;
        off += (bytes + 255) & ~(size_t)255;
        return o;
    };
    size_t o_cntU = take((size_t)NU * 4);
    size_t o_cntI = take((size_t)NI * 4);
    size_t o_aggU = take((size_t)NU * HH * 4);
    size_t o_aggI = take((size_t)NI * HH * 4);
    size_t zero1_end = off;
    size_t o_Su = take((size_t)NU * HH * 4);
    size_t o_Si = take((size_t)NI * HH * 4);
    size_t o_user1 = take((size_t)NU * HH * 4);
    size_t o_item1 = take((size_t)NI * HH * 4);
    (void)ws_size; (void)in_sizes; (void)n_in; (void)out_size;

    float* cntU = (float*)(base + o_cntU);
    float* cntI = (float*)(base + o_cntI);
    float* aggU = (float*)(base + o_aggU);
    float* aggI = (float*)(base + o_aggI);
    float* Su   = (float*)(base + o_Su);
    float* Si   = (float*)(base + o_Si);
    float* user1 = (float*)(base + o_user1);
    float* item1 = (float*)(base + o_item1);

    // ---- zero counts + layer-0 accumulators ----
    hipMemsetAsync(base, 0, zero1_end, stream);
    count_k<<<NE / 256, 256, 0, stream>>>(eu, ei, cntU, cntI);

    // ---- layer 0 ----
    proj128_k<<<NU / 8, 256, 0, stream>>>(x_user, wl0_ui, Su);
    proj128_k<<<NI / 8, 256, 0, stream>>>(x_item, wl0_iu, Si);
    scatter2_k<<<(NE * 32) / 256, 256, 0, stream>>>(eu, ei, Su, Si, aggI, aggU);
    finish128_k<<<NI / 8, 256, 0, stream>>>(aggI, cntI, b0_ui, x_item, wr0_ui, item1);
    finish128_k<<<NU / 8, 256, 0, stream>>>(aggU, cntU, b0_iu, x_user, wr0_iu, user1);

    // ---- layer 1 ----
    hipMemsetAsync(base + o_aggU, 0, zero1_end - o_aggU, stream);
    proj32_k<<<NU / 8, 256, 0, stream>>>(user1, wl1_ui, Su);
    proj32_k<<<NI / 8, 256, 0, stream>>>(item1, wl1_iu, Si);
    scatter2_k<<<(NE * 32) / 256, 256, 0, stream>>>(eu, ei, Su, Si, aggI, aggU);
    finish32_k<<<NI / 8, 256, 0, stream>>>(aggI, cntI, b1_ui, item1, wr1_ui, aggI);
    finish32_k<<<NU / 8, 256, 0, stream>>>(aggU, cntU, b1_iu, user1, wr1_iu, aggU);

    // ---- final projections ----
    final_k<<<NU / 8, 256, 0, stream>>>(aggU, wp_user, bp_user, out);
    final_k<<<NI / 8, 256, 0, stream>>>(aggI, wp_item, bp_item, out + (size_t)NU * HH);
}

// Round 5
// 610.032 us; speedup vs baseline: 1.4705x; 1.4705x over previous
//
#include <hip/hip_runtime.h>
#include <hip/hip_bf16.h>

#define NU 100000
#define NI 50000
#define NE 819200
#define FIN 128
#define HH 32
#define CHUNK 1024

// ================= CSR build =================

// int degree counts into cur arrays (later reused as fill cursors)
__global__ void degcnt_k(const int* __restrict__ eu, const int* __restrict__ ei,
                         int* __restrict__ curU, int* __restrict__ curI) {
    int e = blockIdx.x * 256 + threadIdx.x;
    int u = eu[e], i = ei[e];
    atomicAdd(curU + u, 1);
    atomicAdd(curI + i, 1);
}

// per-chunk (1024) exclusive scan; chunk totals -> part
__global__ void scanA_k(const int* __restrict__ src, int n,
                        int* __restrict__ dst, int* __restrict__ part) {
    __shared__ int ts[256];
    int t = threadIdx.x, b = blockIdx.x;
    int base = b * CHUNK + t * 4;
    int v0 = 0, v1 = 0, v2 = 0, v3 = 0;
    if (base + 0 < n) v0 = src[base + 0];
    if (base + 1 < n) v1 = src[base + 1];
    if (base + 2 < n) v2 = src[base + 2];
    if (base + 3 < n) v3 = src[base + 3];
    int s = v0 + v1 + v2 + v3;
    ts[t] = s;
    __syncthreads();
    int incl = s;
    for (int off = 1; off < 256; off <<= 1) {
        int y = (t >= off) ? ts[t - off] : 0;
        __syncthreads();
        incl += y;
        ts[t] = incl;
        __syncthreads();
    }
    if (t == 255) part[b] = incl;
    int r = incl - s;   // exclusive
    if (base + 0 < n) dst[base + 0] = r; r += v0;
    if (base + 1 < n) dst[base + 1] = r; r += v1;
    if (base + 2 < n) dst[base + 2] = r; r += v2;
    if (base + 3 < n) dst[base + 3] = r;
}

// exclusive scan of both partial arrays (nb <= 256 each), single block
__global__ void scanB_k(int* __restrict__ pU, int nU, int* __restrict__ pI, int nI) {
    __shared__ int ts[256];
    int t = threadIdx.x;
    for (int a = 0; a < 2; ++a) {
        int* p = a ? pI : pU;
        int nb = a ? nI : nU;
        int v = (t < nb) ? p[t] : 0;
        ts[t] = v;
        __syncthreads();
        int incl = v;
        for (int off = 1; off < 256; off <<= 1) {
            int y = (t >= off) ? ts[t - off] : 0;
            __syncthreads();
            incl += y;
            ts[t] = incl;
            __syncthreads();
        }
        if (t < nb) p[t] = incl - v;
        __syncthreads();
    }
}

// add chunk offsets; copy to cursor; set rs[n] = NE
__global__ void scanC_k(int* __restrict__ rs, const int* __restrict__ part, int n,
                        int* __restrict__ cur) {
    int i = blockIdx.x * 256 + threadIdx.x;
    if (i < n) {
        int v = rs[i] + part[i >> 10];
        rs[i] = v;
        cur[i] = v;
    } else if (i == n) {
        rs[n] = NE;
    }
}

__global__ void fill_k(const int* __restrict__ eu, const int* __restrict__ ei,
                       int* __restrict__ curU, int* __restrict__ curI,
                       int* __restrict__ csrU, int* __restrict__ csrI) {
    int e = blockIdx.x * 256 + threadIdx.x;
    int u = eu[e], i = ei[e];
    int s1 = atomicAdd(curI + i, 1);
    csrI[s1] = u;
    int s2 = atomicAdd(curU + u, 1);
    csrU[s2] = i;
}

// ================= projections =================

// S = X@Wl^T, R = X@Wr^T for 128-wide X. block 1024 = 32 nodes x 32 ch.
__global__ __launch_bounds__(1024) void projLR128_k(const float* __restrict__ X,
                                                    const float* __restrict__ Wl,
                                                    const float* __restrict__ Wr,
                                                    float* __restrict__ S,
                                                    float* __restrict__ R, int N) {
    __shared__ float sWlT[FIN * 33];   // [k][o], stride 33 -> conflict-free reads
    __shared__ float sWrT[FIN * 33];
    __shared__ float sX[32][129];
    int tid = threadIdx.x;
    {
        float4 a = ((const float4*)Wl)[tid];
        float4 b = ((const float4*)Wr)[tid];
        int e0 = tid * 4;
        int o = e0 >> 7, k = e0 & 127;
        sWlT[(k + 0) * 33 + o] = a.x;
        sWlT[(k + 1) * 33 + o] = a.y;
        sWlT[(k + 2) * 33 + o] = a.z;
        sWlT[(k + 3) * 33 + o] = a.w;
        sWrT[(k + 0) * 33 + o] = b.x;
        sWrT[(k + 1) * 33 + o] = b.y;
        sWrT[(k + 2) * 33 + o] = b.z;
        sWrT[(k + 3) * 33 + o] = b.w;
    }
    int n0 = blockIdx.x * 32;
    int n = tid >> 5, c = tid & 31;
    {
        int k4 = c * 4;
        if (n0 + n < N) {
            float4 v = *(const float4*)(X + (size_t)(n0 + n) * FIN + k4);
            sX[n][k4 + 0] = v.x; sX[n][k4 + 1] = v.y;
            sX[n][k4 + 2] = v.z; sX[n][k4 + 3] = v.w;
        }
    }
    __syncthreads();
    if (n0 + n < N) {
        float aL = 0.f, aR = 0.f;
#pragma unroll
        for (int k = 0; k < FIN; ++k) {
            float x = sX[n][k];
            aL += x * sWlT[k * 33 + c];
            aR += x * sWrT[k * 33 + c];
        }
        S[(size_t)(n0 + n) * HH + c] = aL;
        R[(size_t)(n0 + n) * HH + c] = aR;
    }
}

// S = X@Wl^T, R = X@Wr^T for 32-wide X; R may alias X (in-place, node-local).
__global__ __launch_bounds__(1024) void projLR32_k(const float* __restrict__ X,
                                                   const float* __restrict__ Wl,
                                                   const float* __restrict__ Wr,
                                                   float* __restrict__ S,
                                                   float* __restrict__ Rout, int N) {
    __shared__ float sWlT[HH * 33];
    __shared__ float sWrT[HH * 33];
    __shared__ float sX[32][33];
    int tid = threadIdx.x;
    {
        int o = tid >> 5, k = tid & 31;
        sWlT[k * 33 + o] = Wl[tid];
        sWrT[k * 33 + o] = Wr[tid];
    }
    int n0 = blockIdx.x * 32;
    int n = tid >> 5, c = tid & 31;
    int node = n0 + n;
    if (node < N) sX[n][c] = X[(size_t)node * HH + c];
    __syncthreads();
    if (node < N) {
        float aL = 0.f, aR = 0.f;
#pragma unroll
        for (int k = 0; k < HH; ++k) {
            float x = sX[n][k];
            aL += x * sWlT[k * 33 + c];
            aR += x * sWrT[k * 33 + c];
        }
        S[(size_t)node * HH + c] = aL;
        Rout[(size_t)node * HH + c] = aR;
    }
}

// ================= pulls =================

// h1 = relu(l2norm(mean_gather(S) + R + b)); written in place over R.
__global__ void pull0_k(const int* __restrict__ csr, const int* __restrict__ rs,
                        const float* __restrict__ S, float* __restrict__ R,
                        const float* __restrict__ b) {
    int tid = threadIdx.x;
    int n = blockIdx.x * 8 + (tid >> 5);
    int c = tid & 31;
    int s0 = rs[n], s1 = rs[n + 1];
    float acc = 0.f;
    for (int j = s0; j < s1; ++j) {
        int src = csr[j];
        acc += S[(size_t)src * HH + c];
    }
    float deg = (float)(s1 - s0);
    deg = deg > 1.f ? deg : 1.f;
    float v = acc / deg + R[(size_t)n * HH + c] + b[c];
    float ss = v * v;
    ss += __shfl_xor(ss, 1);
    ss += __shfl_xor(ss, 2);
    ss += __shfl_xor(ss, 4);
    ss += __shfl_xor(ss, 8);
    ss += __shfl_xor(ss, 16);
    float nrm = sqrtf(ss);
    nrm = nrm > 1e-12f ? nrm : 1e-12f;
    v = v / nrm;
    v = v > 0.f ? v : 0.f;
    R[(size_t)n * HH + c] = v;
}

// h2 = relu(l2norm(mean_gather(S) + R + b1)); out = l2norm(h2@Wp^T + bp)
__global__ void pull1final_k(const int* __restrict__ csr, const int* __restrict__ rs,
                             const float* __restrict__ S, const float* __restrict__ R,
                             const float* __restrict__ b1,
                             const float* __restrict__ Wp, const float* __restrict__ bp,
                             float* __restrict__ out) {
    __shared__ float sWpT[HH * 33];
    __shared__ float sH[8][33];
    int tid = threadIdx.x;
    for (int idx = tid; idx < HH * HH; idx += 256) {
        int o = idx >> 5, k = idx & 31;
        sWpT[k * 33 + o] = Wp[idx];
    }
    int g = tid >> 5;
    int n = blockIdx.x * 8 + g;
    int c = tid & 31;
    int s0 = rs[n], s1 = rs[n + 1];
    float acc = 0.f;
    for (int j = s0; j < s1; ++j) {
        int src = csr[j];
        acc += S[(size_t)src * HH + c];
    }
    float deg = (float)(s1 - s0);
    deg = deg > 1.f ? deg : 1.f;
    float v = acc / deg + R[(size_t)n * HH + c] + b1[c];
    float ss = v * v;
    ss += __shfl_xor(ss, 1);
    ss += __shfl_xor(ss, 2);
    ss += __shfl_xor(ss, 4);
    ss += __shfl_xor(ss, 8);
    ss += __shfl_xor(ss, 16);
    float nrm = sqrtf(ss);
    nrm = nrm > 1e-12f ? nrm : 1e-12f;
    v = v / nrm;
    v = v > 0.f ? v : 0.f;
    sH[g][c] = v;
    __syncthreads();
    float a2 = bp[c];
#pragma unroll
    for (int k = 0; k < HH; ++k) a2 += sH[g][k] * sWpT[k * 33 + c];
    float s2 = a2 * a2;
    s2 += __shfl_xor(s2, 1);
    s2 += __shfl_xor(s2, 2);
    s2 += __shfl_xor(s2, 4);
    s2 += __shfl_xor(s2, 8);
    s2 += __shfl_xor(s2, 16);
    float nrm2 = sqrtf(s2);
    nrm2 = nrm2 > 1e-12f ? nrm2 : 1e-12f;
    out[(size_t)n * HH + c] = a2 / nrm2;
}

// ================= host =================

extern "C" void kernel_launch(void* const* d_in, const int* in_sizes, int n_in,
                              void* d_out, int out_size, void* d_ws, size_t ws_size,
                              hipStream_t stream) {
    const float* x_user = (const float*)d_in[0];
    const float* x_item = (const float*)d_in[1];
    const int* eu = (const int*)d_in[2];
    const int* ei = (const int*)d_in[3];
    const float* wl0_ui = (const float*)d_in[4];
    const float* b0_ui  = (const float*)d_in[5];
    const float* wr0_ui = (const float*)d_in[6];
    const float* wl0_iu = (const float*)d_in[7];
    const float* b0_iu  = (const float*)d_in[8];
    const float* wr0_iu = (const float*)d_in[9];
    const float* wl1_ui = (const float*)d_in[10];
    const float* b1_ui  = (const float*)d_in[11];
    const float* wr1_ui = (const float*)d_in[12];
    const float* wl1_iu = (const float*)d_in[13];
    const float* b1_iu  = (const float*)d_in[14];
    const float* wr1_iu = (const float*)d_in[15];
    const float* wp_user = (const float*)d_in[16];
    const float* bp_user = (const float*)d_in[17];
    const float* wp_item = (const float*)d_in[18];
    const float* bp_item = (const float*)d_in[19];
    float* out = (float*)d_out;
    (void)in_sizes; (void)n_in; (void)out_size; (void)ws_size;

    char* base = (char*)d_ws;
    size_t off = 0;
    auto take = [&](size_t bytes) -> size_t {
        size_t o = off;
        off += (bytes + 255) & ~(size_t)255;
        return o;
    };
    size_t o_curU = take((size_t)NU * 4);
    size_t o_curI = take((size_t)NI * 4);
    size_t zero_end = off;                       // memset region: cursors only
    size_t o_rsU  = take((size_t)(NU + 1) * 4);
    size_t o_rsI  = take((size_t)(NI + 1) * 4);
    size_t o_partU = take(256 * 4);
    size_t o_partI = take(256 * 4);
    size_t o_csrU = take((size_t)NE * 4);
    size_t o_csrI = take((size_t)NE * 4);
    size_t o_Su = take((size_t)NU * HH * 4);
    size_t o_Si = take((size_t)NI * HH * 4);
    size_t o_Ru = take((size_t)NU * HH * 4);
    size_t o_Ri = take((size_t)NI * HH * 4);

    int* curU = (int*)(base + o_curU);
    int* curI = (int*)(base + o_curI);
    int* rsU  = (int*)(base + o_rsU);
    int* rsI  = (int*)(base + o_rsI);
    int* partU = (int*)(base + o_partU);
    int* partI = (int*)(base + o_partI);
    int* csrU = (int*)(base + o_csrU);
    int* csrI = (int*)(base + o_csrI);
    float* Su = (float*)(base + o_Su);
    float* Si = (float*)(base + o_Si);
    float* Ru = (float*)(base + o_Ru);
    float* Ri = (float*)(base + o_Ri);

    const int nbU = (NU + CHUNK - 1) / CHUNK;   // 98
    const int nbI = (NI + CHUNK - 1) / CHUNK;   // 49

    // ---- CSR build (shared by both layers) ----
    hipMemsetAsync(base, 0, zero_end, stream);
    degcnt_k<<<NE / 256, 256, 0, stream>>>(eu, ei, curU, curI);
    scanA_k<<<nbU, 256, 0, stream>>>(curU, NU, rsU, partU);
    scanA_k<<<nbI, 256, 0, stream>>>(curI, NI, rsI, partI);
    scanB_k<<<1, 256, 0, stream>>>(partU, nbU, partI, nbI);
    scanC_k<<<(NU + 256) / 256, 256, 0, stream>>>(rsU, partU, NU, curU);
    scanC_k<<<(NI + 256) / 256, 256, 0, stream>>>(rsI, partI, NI, curI);
    fill_k<<<NE / 256, 256, 0, stream>>>(eu, ei, curU, curI, csrU, csrI);

    // ---- layer 0 ----
    projLR128_k<<<(NU + 31) / 32, 1024, 0, stream>>>(x_user, wl0_ui, wr0_iu, Su, Ru, NU);
    projLR128_k<<<(NI + 31) / 32, 1024, 0, stream>>>(x_item, wl0_iu, wr0_ui, Si, Ri, NI);
    pull0_k<<<NI / 8, 256, 0, stream>>>(csrI, rsI, Su, Ri, b0_ui);   // item1 -> Ri
    pull0_k<<<NU / 8, 256, 0, stream>>>(csrU, rsU, Si, Ru, b0_iu);   // user1 -> Ru

    // ---- layer 1 projections (in-place R) ----
    projLR32_k<<<(NU + 31) / 32, 1024, 0, stream>>>(Ru, wl1_ui, wr1_iu, Su, Ru, NU);
    projLR32_k<<<(NI + 31) / 32, 1024, 0, stream>>>(Ri, wl1_iu, wr1_ui, Si, Ri, NI);

    // ---- layer 1 pulls + final projection fused ----
    pull1final_k<<<NI / 8, 256, 0, stream>>>(csrI, rsI, Su, Ri, b1_ui,
                                             wp_item, bp_item, out + (size_t)NU * HH);
    pull1final_k<<<NU / 8, 256, 0, stream>>>(csrU, rsU, Si, Ru, b1_iu,
                                             wp_user, bp_user, out);
}

// Round 8
// 516.038 us; speedup vs baseline: 1.7384x; 1.1821x over previous
//
#include <hip/hip_runtime.h>
#include <hip/hip_bf16.h>

#define NU 100000
#define NI 50000
#define NE 819200
#define FIN 128
#define HH 32
#define CHUNK 1024

// ================= CSR build =================

// degree counts, 4 edges/thread (int4), non-returning atomics pipeline freely
__global__ void degcnt_k(const int4* __restrict__ eu4, const int4* __restrict__ ei4,
                         int* __restrict__ curU, int* __restrict__ curI) {
    int t = blockIdx.x * 256 + threadIdx.x;        // t in [0, NE/4)
    int4 u = eu4[t];
    int4 i = ei4[t];
    atomicAdd(curU + u.x, 1);
    atomicAdd(curU + u.y, 1);
    atomicAdd(curU + u.z, 1);
    atomicAdd(curU + u.w, 1);
    atomicAdd(curI + i.x, 1);
    atomicAdd(curI + i.y, 1);
    atomicAdd(curI + i.z, 1);
    atomicAdd(curI + i.w, 1);
}

// per-chunk (1024) exclusive scan; chunk totals -> part
__global__ void scanA_k(const int* __restrict__ src, int n,
                        int* __restrict__ dst, int* __restrict__ part) {
    __shared__ int ts[256];
    int t = threadIdx.x, b = blockIdx.x;
    int base = b * CHUNK + t * 4;
    int v0 = 0, v1 = 0, v2 = 0, v3 = 0;
    if (base + 0 < n) v0 = src[base + 0];
    if (base + 1 < n) v1 = src[base + 1];
    if (base + 2 < n) v2 = src[base + 2];
    if (base + 3 < n) v3 = src[base + 3];
    int s = v0 + v1 + v2 + v3;
    ts[t] = s;
    __syncthreads();
    int incl = s;
    for (int off = 1; off < 256; off <<= 1) {
        int y = (t >= off) ? ts[t - off] : 0;
        __syncthreads();
        incl += y;
        ts[t] = incl;
        __syncthreads();
    }
    if (t == 255) part[b] = incl;
    int r = incl - s;   // exclusive
    if (base + 0 < n) dst[base + 0] = r; r += v0;
    if (base + 1 < n) dst[base + 1] = r; r += v1;
    if (base + 2 < n) dst[base + 2] = r; r += v2;
    if (base + 3 < n) dst[base + 3] = r;
}

// exclusive scan of both partial arrays (nb <= 256 each), single block
__global__ void scanB_k(int* __restrict__ pU, int nU, int* __restrict__ pI, int nI) {
    __shared__ int ts[256];
    int t = threadIdx.x;
    for (int a = 0; a < 2; ++a) {
        int* p = a ? pI : pU;
        int nb = a ? nI : nU;
        int v = (t < nb) ? p[t] : 0;
        ts[t] = v;
        __syncthreads();
        int incl = v;
        for (int off = 1; off < 256; off <<= 1) {
            int y = (t >= off) ? ts[t - off] : 0;
            __syncthreads();
            incl += y;
            ts[t] = incl;
            __syncthreads();
        }
        if (t < nb) p[t] = incl - v;
        __syncthreads();
    }
}

// add chunk offsets; copy to cursor; set rs[n] = NE
__global__ void scanC_k(int* __restrict__ rs, const int* __restrict__ part, int n,
                        int* __restrict__ cur) {
    int i = blockIdx.x * 256 + threadIdx.x;
    if (i < n) {
        int v = rs[i] + part[i >> 10];
        rs[i] = v;
        cur[i] = v;
    } else if (i == n) {
        rs[n] = NE;
    }
}

// CSR fill, 4 edges/thread: 8 independent returning atomics in flight, then 8 stores
__global__ void fill_k(const int4* __restrict__ eu4, const int4* __restrict__ ei4,
                       int* __restrict__ curU, int* __restrict__ curI,
                       int* __restrict__ csrU, int* __restrict__ csrI) {
    int t = blockIdx.x * 256 + threadIdx.x;        // t in [0, NE/4)
    int4 u = eu4[t];
    int4 i = ei4[t];
    int a0 = atomicAdd(curI + i.x, 1);
    int a1 = atomicAdd(curI + i.y, 1);
    int a2 = atomicAdd(curI + i.z, 1);
    int a3 = atomicAdd(curI + i.w, 1);
    int b0 = atomicAdd(curU + u.x, 1);
    int b1 = atomicAdd(curU + u.y, 1);
    int b2 = atomicAdd(curU + u.z, 1);
    int b3 = atomicAdd(curU + u.w, 1);
    csrI[a0] = u.x;
    csrI[a1] = u.y;
    csrI[a2] = u.z;
    csrI[a3] = u.w;
    csrU[b0] = i.x;
    csrU[b1] = i.y;
    csrU[b2] = i.z;
    csrU[b3] = i.w;
}

// ================= projections =================

// S = X@Wl^T, R = X@Wr^T for 128-wide X. block 1024 = 32 nodes x 32 ch.
__global__ __launch_bounds__(1024) void projLR128_k(const float* __restrict__ X,
                                                    const float* __restrict__ Wl,
                                                    const float* __restrict__ Wr,
                                                    float* __restrict__ S,
                                                    float* __restrict__ R, int N) {
    __shared__ float sWlT[FIN * 33];   // [k][o], stride 33 -> conflict-free reads
    __shared__ float sWrT[FIN * 33];
    __shared__ float sX[32][129];
    int tid = threadIdx.x;
    {
        float4 a = ((const float4*)Wl)[tid];
        float4 b = ((const float4*)Wr)[tid];
        int e0 = tid * 4;
        int o = e0 >> 7, k = e0 & 127;
        sWlT[(k + 0) * 33 + o] = a.x;
        sWlT[(k + 1) * 33 + o] = a.y;
        sWlT[(k + 2) * 33 + o] = a.z;
        sWlT[(k + 3) * 33 + o] = a.w;
        sWrT[(k + 0) * 33 + o] = b.x;
        sWrT[(k + 1) * 33 + o] = b.y;
        sWrT[(k + 2) * 33 + o] = b.z;
        sWrT[(k + 3) * 33 + o] = b.w;
    }
    int n0 = blockIdx.x * 32;
    int n = tid >> 5, c = tid & 31;
    {
        int k4 = c * 4;
        if (n0 + n < N) {
            float4 v = *(const float4*)(X + (size_t)(n0 + n) * FIN + k4);
            sX[n][k4 + 0] = v.x; sX[n][k4 + 1] = v.y;
            sX[n][k4 + 2] = v.z; sX[n][k4 + 3] = v.w;
        }
    }
    __syncthreads();
    if (n0 + n < N) {
        float aL = 0.f, aR = 0.f;
#pragma unroll
        for (int k = 0; k < FIN; ++k) {
            float x = sX[n][k];
            aL += x * sWlT[k * 33 + c];
            aR += x * sWrT[k * 33 + c];
        }
        S[(size_t)(n0 + n) * HH + c] = aL;
        R[(size_t)(n0 + n) * HH + c] = aR;
    }
}

// S = X@Wl^T, R = X@Wr^T for 32-wide X; R may alias X (in-place, node-local).
__global__ __launch_bounds__(1024) void projLR32_k(const float* __restrict__ X,
                                                   const float* __restrict__ Wl,
                                                   const float* __restrict__ Wr,
                                                   float* __restrict__ S,
                                                   float* __restrict__ Rout, int N) {
    __shared__ float sWlT[HH * 33];
    __shared__ float sWrT[HH * 33];
    __shared__ float sX[32][33];
    int tid = threadIdx.x;
    {
        int o = tid >> 5, k = tid & 31;
        sWlT[k * 33 + o] = Wl[tid];
        sWrT[k * 33 + o] = Wr[tid];
    }
    int n0 = blockIdx.x * 32;
    int n = tid >> 5, c = tid & 31;
    int node = n0 + n;
    if (node < N) sX[n][c] = X[(size_t)node * HH + c];
    __syncthreads();
    if (node < N) {
        float aL = 0.f, aR = 0.f;
#pragma unroll
        for (int k = 0; k < HH; ++k) {
            float x = sX[n][k];
            aL += x * sWlT[k * 33 + c];
            aR += x * sWrT[k * 33 + c];
        }
        S[(size_t)node * HH + c] = aL;
        Rout[(size_t)node * HH + c] = aR;
    }
}

// ================= pulls =================

// h1 = relu(l2norm(mean_gather(S) + R + b)); written in place over R.
__global__ void pull0_k(const int* __restrict__ csr, const int* __restrict__ rs,
                        const float* __restrict__ S, float* __restrict__ R,
                        const float* __restrict__ b) {
    int tid = threadIdx.x;
    int n = blockIdx.x * 8 + (tid >> 5);
    int c = tid & 31;
    int s0 = rs[n], s1 = rs[n + 1];
    float acc = 0.f, acc2 = 0.f;
    int j = s0;
    for (; j + 1 < s1; j += 2) {
        int srcA = csr[j];
        int srcB = csr[j + 1];
        acc  += S[(size_t)srcA * HH + c];
        acc2 += S[(size_t)srcB * HH + c];
    }
    if (j < s1) acc += S[(size_t)csr[j] * HH + c];
    acc += acc2;
    float deg = (float)(s1 - s0);
    deg = deg > 1.f ? deg : 1.f;
    float v = acc / deg + R[(size_t)n * HH + c] + b[c];
    float ss = v * v;
    ss += __shfl_xor(ss, 1);
    ss += __shfl_xor(ss, 2);
    ss += __shfl_xor(ss, 4);
    ss += __shfl_xor(ss, 8);
    ss += __shfl_xor(ss, 16);
    float nrm = sqrtf(ss);
    nrm = nrm > 1e-12f ? nrm : 1e-12f;
    v = v / nrm;
    v = v > 0.f ? v : 0.f;
    R[(size_t)n * HH + c] = v;
}

// h2 = relu(l2norm(mean_gather(S) + R + b1)); out = l2norm(h2@Wp^T + bp)
__global__ void pull1final_k(const int* __restrict__ csr, const int* __restrict__ rs,
                             const float* __restrict__ S, const float* __restrict__ R,
                             const float* __restrict__ b1,
                             const float* __restrict__ Wp, const float* __restrict__ bp,
                             float* __restrict__ out) {
    __shared__ float sWpT[HH * 33];
    __shared__ float sH[8][33];
    int tid = threadIdx.x;
    for (int idx = tid; idx < HH * HH; idx += 256) {
        int o = idx >> 5, k = idx & 31;
        sWpT[k * 33 + o] = Wp[idx];
    }
    int g = tid >> 5;
    int n = blockIdx.x * 8 + g;
    int c = tid & 31;
    int s0 = rs[n], s1 = rs[n + 1];
    float acc = 0.f, acc2 = 0.f;
    int j = s0;
    for (; j + 1 < s1; j += 2) {
        int srcA = csr[j];
        int srcB = csr[j + 1];
        acc  += S[(size_t)srcA * HH + c];
        acc2 += S[(size_t)srcB * HH + c];
    }
    if (j < s1) acc += S[(size_t)csr[j] * HH + c];
    acc += acc2;
    float deg = (float)(s1 - s0);
    deg = deg > 1.f ? deg : 1.f;
    float v = acc / deg + R[(size_t)n * HH + c] + b1[c];
    float ss = v * v;
    ss += __shfl_xor(ss, 1);
    ss += __shfl_xor(ss, 2);
    ss += __shfl_xor(ss, 4);
    ss += __shfl_xor(ss, 8);
    ss += __shfl_xor(ss, 16);
    float nrm = sqrtf(ss);
    nrm = nrm > 1e-12f ? nrm : 1e-12f;
    v = v / nrm;
    v = v > 0.f ? v : 0.f;
    sH[g][c] = v;
    __syncthreads();
    float a2 = bp[c];
#pragma unroll
    for (int k = 0; k < HH; ++k) a2 += sH[g][k] * sWpT[k * 33 + c];
    float s2 = a2 * a2;
    s2 += __shfl_xor(s2, 1);
    s2 += __shfl_xor(s2, 2);
    s2 += __shfl_xor(s2, 4);
    s2 += __shfl_xor(s2, 8);
    s2 += __shfl_xor(s2, 16);
    float nrm2 = sqrtf(s2);
    nrm2 = nrm2 > 1e-12f ? nrm2 : 1e-12f;
    out[(size_t)n * HH + c] = a2 / nrm2;
}

// ================= host =================

extern "C" void kernel_launch(void* const* d_in, const int* in_sizes, int n_in,
                              void* d_out, int out_size, void* d_ws, size_t ws_size,
                              hipStream_t stream) {
    const float* x_user = (const float*)d_in[0];
    const float* x_item = (const float*)d_in[1];
    const int* eu = (const int*)d_in[2];
    const int* ei = (const int*)d_in[3];
    const float* wl0_ui = (const float*)d_in[4];
    const float* b0_ui  = (const float*)d_in[5];
    const float* wr0_ui = (const float*)d_in[6];
    const float* wl0_iu = (const float*)d_in[7];
    const float* b0_iu  = (const float*)d_in[8];
    const float* wr0_iu = (const float*)d_in[9];
    const float* wl1_ui = (const float*)d_in[10];
    const float* b1_ui  = (const float*)d_in[11];
    const float* wr1_ui = (const float*)d_in[12];
    const float* wl1_iu = (const float*)d_in[13];
    const float* b1_iu  = (const float*)d_in[14];
    const float* wr1_iu = (const float*)d_in[15];
    const float* wp_user = (const float*)d_in[16];
    const float* bp_user = (const float*)d_in[17];
    const float* wp_item = (const float*)d_in[18];
    const float* bp_item = (const float*)d_in[19];
    float* out = (float*)d_out;
    (void)in_sizes; (void)n_in; (void)out_size; (void)ws_size;

    char* base = (char*)d_ws;
    size_t off = 0;
    auto take = [&](size_t bytes) -> size_t {
        size_t o = off;
        off += (bytes + 255) & ~(size_t)255;
        return o;
    };
    size_t o_curU = take((size_t)NU * 4);
    size_t o_curI = take((size_t)NI * 4);
    size_t zero_end = off;                       // memset region: cursors only
    size_t o_rsU  = take((size_t)(NU + 1) * 4);
    size_t o_rsI  = take((size_t)(NI + 1) * 4);
    size_t o_partU = take(256 * 4);
    size_t o_partI = take(256 * 4);
    size_t o_csrU = take((size_t)NE * 4);
    size_t o_csrI = take((size_t)NE * 4);
    size_t o_Su = take((size_t)NU * HH * 4);
    size_t o_Si = take((size_t)NI * HH * 4);
    size_t o_Ru = take((size_t)NU * HH * 4);
    size_t o_Ri = take((size_t)NI * HH * 4);

    int* curU = (int*)(base + o_curU);
    int* curI = (int*)(base + o_curI);
    int* rsU  = (int*)(base + o_rsU);
    int* rsI  = (int*)(base + o_rsI);
    int* partU = (int*)(base + o_partU);
    int* partI = (int*)(base + o_partI);
    int* csrU = (int*)(base + o_csrU);
    int* csrI = (int*)(base + o_csrI);
    float* Su = (float*)(base + o_Su);
    float* Si = (float*)(base + o_Si);
    float* Ru = (float*)(base + o_Ru);
    float* Ri = (float*)(base + o_Ri);

    const int nbU = (NU + CHUNK - 1) / CHUNK;   // 98
    const int nbI = (NI + CHUNK - 1) / CHUNK;   // 49

    // ---- CSR build (shared by both layers) ----
    hipMemsetAsync(base, 0, zero_end, stream);
    degcnt_k<<<NE / 4 / 256, 256, 0, stream>>>((const int4*)eu, (const int4*)ei, curU, curI);
    scanA_k<<<nbU, 256, 0, stream>>>(curU, NU, rsU, partU);
    scanA_k<<<nbI, 256, 0, stream>>>(curI, NI, rsI, partI);
    scanB_k<<<1, 256, 0, stream>>>(partU, nbU, partI, nbI);
    scanC_k<<<(NU + 256) / 256, 256, 0, stream>>>(rsU, partU, NU, curU);
    scanC_k<<<(NI + 256) / 256, 256, 0, stream>>>(rsI, partI, NI, curI);
    fill_k<<<NE / 4 / 256, 256, 0, stream>>>((const int4*)eu, (const int4*)ei,
                                             curU, curI, csrU, csrI);

    // ---- layer 0 ----
    projLR128_k<<<(NU + 31) / 32, 1024, 0, stream>>>(x_user, wl0_ui, wr0_iu, Su, Ru, NU);
    projLR128_k<<<(NI + 31) / 32, 1024, 0, stream>>>(x_item, wl0_iu, wr0_ui, Si, Ri, NI);
    pull0_k<<<NI / 8, 256, 0, stream>>>(csrI, rsI, Su, Ri, b0_ui);   // item1 -> Ri
    pull0_k<<<NU / 8, 256, 0, stream>>>(csrU, rsU, Si, Ru, b0_iu);   // user1 -> Ru

    // ---- layer 1 projections (in-place R) ----
    projLR32_k<<<(NU + 31) / 32, 1024, 0, stream>>>(Ru, wl1_ui, wr1_iu, Su, Ru, NU);
    projLR32_k<<<(NI + 31) / 32, 1024, 0, stream>>>(Ri, wl1_iu, wr1_ui, Si, Ri, NI);

    // ---- layer 1 pulls + final projection fused ----
    pull1final_k<<<NI / 8, 256, 0, stream>>>(csrI, rsI, Su, Ri, b1_ui,
                                             wp_item, bp_item, out + (size_t)NU * HH);
    pull1final_k<<<NU / 8, 256, 0, stream>>>(csrU, rsU, Si, Ru, b1_iu,
                                             wp_user, bp_user, out);
}

// Round 9
// 452.124 us; speedup vs baseline: 1.9841x; 1.1414x over previous
//
#include <hip/hip_runtime.h>

#define NU 100000
#define NI 50000
#define NE 819200
#define FIN 128
#define HH 32
#define CHUNK 1024

#define G_DEG 200       // NE/4/1024
#define G_PU  3125      // NU/32
#define G_PI  1563      // ceil(NI/32)
#define G_FILL 800      // NE/4/256
#define G_P0I 6250      // NI/8
#define G_P0U 12500     // NU/8

// ================= device bodies =================

__device__ __forceinline__ void fill_body(const int4* __restrict__ dst4,
                                          const int4* __restrict__ pay4,
                                          int* __restrict__ cur, int* __restrict__ csr,
                                          int vb) {
    int t = vb * 256 + threadIdx.x;                // t in [0, NE/4)
    int4 d = dst4[t];
    int4 p = pay4[t];
    int a0 = atomicAdd(cur + d.x, 1);
    int a1 = atomicAdd(cur + d.y, 1);
    int a2 = atomicAdd(cur + d.z, 1);
    int a3 = atomicAdd(cur + d.w, 1);
    csr[a0] = p.x;
    csr[a1] = p.y;
    csr[a2] = p.z;
    csr[a3] = p.w;
}

// 1024 threads: 32 nodes x 32 ch
__device__ __forceinline__ void proj128_body(const float* __restrict__ X,
                                             const float* __restrict__ Wl,
                                             const float* __restrict__ Wr,
                                             float* __restrict__ S, float* __restrict__ R,
                                             int N, int vb, float* smem) {
    float* sWlT = smem;                 // [128][33]
    float* sWrT = smem + FIN * 33;
    float* sX   = smem + 2 * FIN * 33;  // [32][129]
    int tid = threadIdx.x;
    {
        float4 a = ((const float4*)Wl)[tid];    // 1024 x float4 = 4096 elems
        float4 b = ((const float4*)Wr)[tid];
        int e0 = tid * 4;
        int o = e0 >> 7, k = e0 & 127;
        sWlT[(k + 0) * 33 + o] = a.x;
        sWlT[(k + 1) * 33 + o] = a.y;
        sWlT[(k + 2) * 33 + o] = a.z;
        sWlT[(k + 3) * 33 + o] = a.w;
        sWrT[(k + 0) * 33 + o] = b.x;
        sWrT[(k + 1) * 33 + o] = b.y;
        sWrT[(k + 2) * 33 + o] = b.z;
        sWrT[(k + 3) * 33 + o] = b.w;
    }
    int n0 = vb * 32;
    int n = tid >> 5, c = tid & 31;
    if (n0 + n < N) {
        int k4 = c * 4;
        float4 v = *(const float4*)(X + (size_t)(n0 + n) * FIN + k4);
        sX[n * 129 + k4 + 0] = v.x;
        sX[n * 129 + k4 + 1] = v.y;
        sX[n * 129 + k4 + 2] = v.z;
        sX[n * 129 + k4 + 3] = v.w;
    }
    __syncthreads();
    if (n0 + n < N) {
        float aL = 0.f, aR = 0.f;
#pragma unroll
        for (int k = 0; k < FIN; ++k) {
            float x = sX[n * 129 + k];
            aL += x * sWlT[k * 33 + c];
            aR += x * sWrT[k * 33 + c];
        }
        S[(size_t)(n0 + n) * HH + c] = aL;
        R[(size_t)(n0 + n) * HH + c] = aR;
    }
}

// 256 threads: 8 nodes x 32 ch (N divisible by 8); R may alias X (row-local)
__device__ __forceinline__ void proj32_body(const float* __restrict__ X,
                                            const float* __restrict__ Wl,
                                            const float* __restrict__ Wr,
                                            float* __restrict__ S, float* __restrict__ R,
                                            int vb, float* smem) {
    float* sWlT = smem;                 // [32][33]
    float* sWrT = smem + HH * 33;
    float* sX   = smem + 2 * HH * 33;   // [8][33]
    int tid = threadIdx.x;
    {
        float4 a = ((const float4*)Wl)[tid];    // 256 x float4 = 1024 elems
        float4 b = ((const float4*)Wr)[tid];
        int e0 = tid * 4;
        int o = e0 >> 5, k = e0 & 31;
        sWlT[(k + 0) * 33 + o] = a.x;
        sWlT[(k + 1) * 33 + o] = a.y;
        sWlT[(k + 2) * 33 + o] = a.z;
        sWlT[(k + 3) * 33 + o] = a.w;
        sWrT[(k + 0) * 33 + o] = b.x;
        sWrT[(k + 1) * 33 + o] = b.y;
        sWrT[(k + 2) * 33 + o] = b.z;
        sWrT[(k + 3) * 33 + o] = b.w;
    }
    int n0 = vb * 8;
    int n = tid >> 5, c = tid & 31;
    sX[n * 33 + c] = X[(size_t)(n0 + n) * HH + c];
    __syncthreads();
    float aL = 0.f, aR = 0.f;
#pragma unroll
    for (int k = 0; k < HH; ++k) {
        float x = sX[n * 33 + k];
        aL += x * sWlT[k * 33 + c];
        aR += x * sWrT[k * 33 + c];
    }
    S[(size_t)(n0 + n) * HH + c] = aL;
    R[(size_t)(n0 + n) * HH + c] = aR;
}

// 256 threads: 8 nodes; h = relu(l2norm(mean + R + b)) written over R
__device__ __forceinline__ void pull0_body(const int* __restrict__ csr,
                                           const int* __restrict__ rs,
                                           const float* __restrict__ S,
                                           float* __restrict__ R,
                                           const float* __restrict__ bias, int vb) {
    int tid = threadIdx.x;
    int n = vb * 8 + (tid >> 5);
    int c = tid & 31;
    int s0 = rs[n], s1 = rs[n + 1];
    float acc = 0.f, acc2 = 0.f;
    int j = s0;
    for (; j + 1 < s1; j += 2) {
        int a = csr[j], b = csr[j + 1];
        acc  += S[(size_t)a * HH + c];
        acc2 += S[(size_t)b * HH + c];
    }
    if (j < s1) acc += S[(size_t)csr[j] * HH + c];
    acc += acc2;
    float deg = (float)(s1 - s0);
    deg = deg > 1.f ? deg : 1.f;
    float v = acc / deg + R[(size_t)n * HH + c] + bias[c];
    float ss = v * v;
    ss += __shfl_xor(ss, 1);
    ss += __shfl_xor(ss, 2);
    ss += __shfl_xor(ss, 4);
    ss += __shfl_xor(ss, 8);
    ss += __shfl_xor(ss, 16);
    float nrm = sqrtf(ss);
    nrm = nrm > 1e-12f ? nrm : 1e-12f;
    v = v / nrm;
    v = v > 0.f ? v : 0.f;
    R[(size_t)n * HH + c] = v;
}

// 256 threads: 8 nodes; h2 = relu(l2norm(mean + R + b1)); out = l2norm(h2@Wp^T + bp)
__device__ __forceinline__ void pull1f_body(const int* __restrict__ csr,
                                            const int* __restrict__ rs,
                                            const float* __restrict__ S,
                                            const float* __restrict__ R,
                                            const float* __restrict__ b1,
                                            const float* __restrict__ Wp,
                                            const float* __restrict__ bp,
                                            float* __restrict__ out, int vb, float* smem) {
    float* sWpT = smem;              // [32][33]
    float* sH   = smem + HH * 33;    // [8][33]
    int tid = threadIdx.x;
    {
        float4 a = ((const float4*)Wp)[tid];
        int e0 = tid * 4;
        int o = e0 >> 5, k = e0 & 31;
        sWpT[(k + 0) * 33 + o] = a.x;
        sWpT[(k + 1) * 33 + o] = a.y;
        sWpT[(k + 2) * 33 + o] = a.z;
        sWpT[(k + 3) * 33 + o] = a.w;
    }
    int g = tid >> 5;
    int n = vb * 8 + g;
    int c = tid & 31;
    int s0 = rs[n], s1 = rs[n + 1];
    float acc = 0.f, acc2 = 0.f;
    int j = s0;
    for (; j + 1 < s1; j += 2) {
        int a = csr[j], b = csr[j + 1];
        acc  += S[(size_t)a * HH + c];
        acc2 += S[(size_t)b * HH + c];
    }
    if (j < s1) acc += S[(size_t)csr[j] * HH + c];
    acc += acc2;
    float deg = (float)(s1 - s0);
    deg = deg > 1.f ? deg : 1.f;
    float v = acc / deg + R[(size_t)n * HH + c] + b1[c];
    float ss = v * v;
    ss += __shfl_xor(ss, 1);
    ss += __shfl_xor(ss, 2);
    ss += __shfl_xor(ss, 4);
    ss += __shfl_xor(ss, 8);
    ss += __shfl_xor(ss, 16);
    float nrm = sqrtf(ss);
    nrm = nrm > 1e-12f ? nrm : 1e-12f;
    v = v / nrm;
    v = v > 0.f ? v : 0.f;
    sH[g * 33 + c] = v;
    __syncthreads();
    float a2 = bp[c];
#pragma unroll
    for (int k = 0; k < HH; ++k) a2 += sH[g * 33 + k] * sWpT[k * 33 + c];
    float s2 = a2 * a2;
    s2 += __shfl_xor(s2, 1);
    s2 += __shfl_xor(s2, 2);
    s2 += __shfl_xor(s2, 4);
    s2 += __shfl_xor(s2, 8);
    s2 += __shfl_xor(s2, 16);
    float nrm2 = sqrtf(s2);
    nrm2 = nrm2 > 1e-12f ? nrm2 : 1e-12f;
    out[(size_t)n * HH + c] = a2 / nrm2;
}

// ================= fused kernels =================

// K1: degcnt || proj128_user || proj128_item
__global__ __launch_bounds__(1024) void k1_k(const int4* __restrict__ eu4,
                                             const int4* __restrict__ ei4,
                                             int* __restrict__ curU, int* __restrict__ curI,
                                             const float* __restrict__ xu,
                                             const float* __restrict__ xi,
                                             const float* __restrict__ wl0_ui,
                                             const float* __restrict__ wr0_iu,
                                             const float* __restrict__ wl0_iu,
                                             const float* __restrict__ wr0_ui,
                                             float* __restrict__ Su, float* __restrict__ Ru,
                                             float* __restrict__ Si, float* __restrict__ Ri) {
    __shared__ float smem[2 * FIN * 33 + 32 * 129];
    int b = blockIdx.x;
    if (b < G_DEG) {
        int t = b * 1024 + threadIdx.x;
        int4 u = eu4[t];
        int4 i = ei4[t];
        atomicAdd(curU + u.x, 1);
        atomicAdd(curU + u.y, 1);
        atomicAdd(curU + u.z, 1);
        atomicAdd(curU + u.w, 1);
        atomicAdd(curI + i.x, 1);
        atomicAdd(curI + i.y, 1);
        atomicAdd(curI + i.z, 1);
        atomicAdd(curI + i.w, 1);
    } else if (b < G_DEG + G_PU) {
        proj128_body(xu, wl0_ui, wr0_iu, Su, Ru, NU, b - G_DEG, smem);
    } else {
        proj128_body(xi, wl0_iu, wr0_ui, Si, Ri, NI, b - G_DEG - G_PU, smem);
    }
}

// K3: fill item-CSR alone
__global__ void k3_k(const int4* __restrict__ eu4, const int4* __restrict__ ei4,
                     int* __restrict__ curI, int* __restrict__ csrI) {
    fill_body(ei4, eu4, curI, csrI, blockIdx.x);
}

// K4: fillU || pull0_item
__global__ void k4_k(const int4* __restrict__ eu4, const int4* __restrict__ ei4,
                     int* __restrict__ curU, int* __restrict__ csrU,
                     const int* __restrict__ csrI, const int* __restrict__ rsI,
                     const float* __restrict__ Su, float* __restrict__ Ri,
                     const float* __restrict__ b0_ui) {
    int b = blockIdx.x;
    if (b < G_FILL) {
        fill_body(eu4, ei4, curU, csrU, b);
    } else {
        pull0_body(csrI, rsI, Su, Ri, b0_ui, b - G_FILL);
    }
}

// K5: pull0_user || proj32(item1)
__global__ void k5_k(const int* __restrict__ csrU, const int* __restrict__ rsU,
                     const float* __restrict__ Si, float* __restrict__ Ru,
                     const float* __restrict__ b0_iu,
                     float* __restrict__ Ri,            // item1 in, item-self out (in place)
                     const float* __restrict__ wl1_iu, const float* __restrict__ wr1_ui,
                     float* __restrict__ Si2) {
    __shared__ float smem[2 * HH * 33 + 8 * 33];
    int b = blockIdx.x;
    if (b < G_P0U) {
        pull0_body(csrU, rsU, Si, Ru, b0_iu, b);
    } else {
        proj32_body(Ri, wl1_iu, wr1_ui, Si2, Ri, b - G_P0U, smem);
    }
}

// K6: proj32(user1)
__global__ void k6_k(float* __restrict__ Ru,            // user1 in, user-self out (in place)
                     const float* __restrict__ wl1_ui, const float* __restrict__ wr1_iu,
                     float* __restrict__ Su2) {
    __shared__ float smem[2 * HH * 33 + 8 * 33];
    proj32_body(Ru, wl1_ui, wr1_iu, Su2, Ru, blockIdx.x, smem);
}

// K7: pull1final_user || pull1final_item
__global__ void k7_k(const int* __restrict__ csrU, const int* __restrict__ rsU,
                     const float* __restrict__ Si2, const float* __restrict__ Ru,
                     const float* __restrict__ b1_iu,
                     const float* __restrict__ wp_user, const float* __restrict__ bp_user,
                     const int* __restrict__ csrI, const int* __restrict__ rsI,
                     const float* __restrict__ Su2, const float* __restrict__ Ri,
                     const float* __restrict__ b1_ui,
                     const float* __restrict__ wp_item, const float* __restrict__ bp_item,
                     float* __restrict__ out) {
    __shared__ float smem[HH * 33 + 8 * 33];
    int b = blockIdx.x;
    if (b < G_P0U) {
        pull1f_body(csrU, rsU, Si2, Ru, b1_iu, wp_user, bp_user, out, b, smem);
    } else {
        pull1f_body(csrI, rsI, Su2, Ri, b1_ui, wp_item, bp_item,
                    out + (size_t)NU * HH, b - G_P0U, smem);
    }
}

// ================= scans (unchanged) =================

__global__ void scanA_k(const int* __restrict__ src, int n,
                        int* __restrict__ dst, int* __restrict__ part) {
    __shared__ int ts[256];
    int t = threadIdx.x, b = blockIdx.x;
    int base = b * CHUNK + t * 4;
    int v0 = 0, v1 = 0, v2 = 0, v3 = 0;
    if (base + 0 < n) v0 = src[base + 0];
    if (base + 1 < n) v1 = src[base + 1];
    if (base + 2 < n) v2 = src[base + 2];
    if (base + 3 < n) v3 = src[base + 3];
    int s = v0 + v1 + v2 + v3;
    ts[t] = s;
    __syncthreads();
    int incl = s;
    for (int off = 1; off < 256; off <<= 1) {
        int y = (t >= off) ? ts[t - off] : 0;
        __syncthreads();
        incl += y;
        ts[t] = incl;
        __syncthreads();
    }
    if (t == 255) part[b] = incl;
    int r = incl - s;
    if (base + 0 < n) dst[base + 0] = r; r += v0;
    if (base + 1 < n) dst[base + 1] = r; r += v1;
    if (base + 2 < n) dst[base + 2] = r; r += v2;
    if (base + 3 < n) dst[base + 3] = r;
}

__global__ void scanB_k(int* __restrict__ pU, int nU, int* __restrict__ pI, int nI) {
    __shared__ int ts[256];
    int t = threadIdx.x;
    for (int a = 0; a < 2; ++a) {
        int* p = a ? pI : pU;
        int nb = a ? nI : nU;
        int v = (t < nb) ? p[t] : 0;
        ts[t] = v;
        __syncthreads();
        int incl = v;
        for (int off = 1; off < 256; off <<= 1) {
            int y = (t >= off) ? ts[t - off] : 0;
            __syncthreads();
            incl += y;
            ts[t] = incl;
            __syncthreads();
        }
        if (t < nb) p[t] = incl - v;
        __syncthreads();
    }
}

__global__ void scanC_k(int* __restrict__ rs, const int* __restrict__ part, int n,
                        int* __restrict__ cur) {
    int i = blockIdx.x * 256 + threadIdx.x;
    if (i < n) {
        int v = rs[i] + part[i >> 10];
        rs[i] = v;
        cur[i] = v;
    } else if (i == n) {
        rs[n] = NE;
    }
}

// ================= host =================

extern "C" void kernel_launch(void* const* d_in, const int* in_sizes, int n_in,
                              void* d_out, int out_size, void* d_ws, size_t ws_size,
                              hipStream_t stream) {
    const float* x_user = (const float*)d_in[0];
    const float* x_item = (const float*)d_in[1];
    const int* eu = (const int*)d_in[2];
    const int* ei = (const int*)d_in[3];
    const float* wl0_ui = (const float*)d_in[4];
    const float* b0_ui  = (const float*)d_in[5];
    const float* wr0_ui = (const float*)d_in[6];
    const float* wl0_iu = (const float*)d_in[7];
    const float* b0_iu  = (const float*)d_in[8];
    const float* wr0_iu = (const float*)d_in[9];
    const float* wl1_ui = (const float*)d_in[10];
    const float* b1_ui  = (const float*)d_in[11];
    const float* wr1_ui = (const float*)d_in[12];
    const float* wl1_iu = (const float*)d_in[13];
    const float* b1_iu  = (const float*)d_in[14];
    const float* wr1_iu = (const float*)d_in[15];
    const float* wp_user = (const float*)d_in[16];
    const float* bp_user = (const float*)d_in[17];
    const float* wp_item = (const float*)d_in[18];
    const float* bp_item = (const float*)d_in[19];
    float* out = (float*)d_out;
    (void)in_sizes; (void)n_in; (void)out_size; (void)ws_size;

    char* base = (char*)d_ws;
    size_t off = 0;
    auto take = [&](size_t bytes) -> size_t {
        size_t o = off;
        off += (bytes + 255) & ~(size_t)255;
        return o;
    };
    size_t o_curU = take((size_t)NU * 4);
    size_t o_curI = take((size_t)NI * 4);
    size_t zero_end = off;                       // memset region: cursors only
    size_t o_rsU  = take((size_t)(NU + 1) * 4);
    size_t o_rsI  = take((size_t)(NI + 1) * 4);
    size_t o_partU = take(256 * 4);
    size_t o_partI = take(256 * 4);
    size_t o_csrU = take((size_t)NE * 4);
    size_t o_csrI = take((size_t)NE * 4);
    size_t o_Su = take((size_t)NU * HH * 4);     // layer0 user->item msgs; reused as Si2
    size_t o_Si = take((size_t)NI * HH * 4);
    size_t o_Ru = take((size_t)NU * HH * 4);
    size_t o_Ri = take((size_t)NI * HH * 4);
    size_t o_Su2 = take((size_t)NU * HH * 4);    // layer1 user->item msgs

    int* curU = (int*)(base + o_curU);
    int* curI = (int*)(base + o_curI);
    int* rsU  = (int*)(base + o_rsU);
    int* rsI  = (int*)(base + o_rsI);
    int* partU = (int*)(base + o_partU);
    int* partI = (int*)(base + o_partI);
    int* csrU = (int*)(base + o_csrU);
    int* csrI = (int*)(base + o_csrI);
    float* Su = (float*)(base + o_Su);
    float* Si = (float*)(base + o_Si);
    float* Ru = (float*)(base + o_Ru);
    float* Ri = (float*)(base + o_Ri);
    float* Su2 = (float*)(base + o_Su2);
    float* Si2 = Su;   // Su free after K4; holds item1@wl1_iu^T

    const int nbU = (NU + CHUNK - 1) / CHUNK;   // 98
    const int nbI = (NI + CHUNK - 1) / CHUNK;   // 49

    hipMemsetAsync(base, 0, zero_end, stream);

    // K1: degcnt || proj128_U || proj128_I
    k1_k<<<G_DEG + G_PU + G_PI, 1024, 0, stream>>>(
        (const int4*)eu, (const int4*)ei, curU, curI,
        x_user, x_item, wl0_ui, wr0_iu, wl0_iu, wr0_ui, Su, Ru, Si, Ri);

    // K2: scans
    scanA_k<<<nbU, 256, 0, stream>>>(curU, NU, rsU, partU);
    scanA_k<<<nbI, 256, 0, stream>>>(curI, NI, rsI, partI);
    scanB_k<<<1, 256, 0, stream>>>(partU, nbU, partI, nbI);
    scanC_k<<<(NU + 256) / 256, 256, 0, stream>>>(rsU, partU, NU, curU);
    scanC_k<<<(NI + 256) / 256, 256, 0, stream>>>(rsI, partI, NI, curI);

    // K3: fill item CSR
    k3_k<<<G_FILL, 256, 0, stream>>>((const int4*)eu, (const int4*)ei, curI, csrI);

    // K4: fillU || pull0_I (item1 -> Ri)
    k4_k<<<G_FILL + G_P0I, 256, 0, stream>>>((const int4*)eu, (const int4*)ei, curU, csrU,
                                             csrI, rsI, Su, Ri, b0_ui);

    // K5: pull0_U (user1 -> Ru) || proj32(item1): Si2 = item1@wl1_iu^T, Ri = item1@wr1_ui^T
    k5_k<<<G_P0U + G_P0I, 256, 0, stream>>>(csrU, rsU, Si, Ru, b0_iu,
                                            Ri, wl1_iu, wr1_ui, Si2);

    // K6: proj32(user1): Su2 = user1@wl1_ui^T, Ru = user1@wr1_iu^T
    k6_k<<<G_P0U, 256, 0, stream>>>(Ru, wl1_ui, wr1_iu, Su2);

    // K7: pull1final_U || pull1final_I -> out
    k7_k<<<G_P0U + G_P0I, 256, 0, stream>>>(csrU, rsU, Si2, Ru, b1_iu, wp_user, bp_user,
                                            csrI, rsI, Su2, Ri, b1_ui, wp_item, bp_item,
                                            out);
}